// Round 12
// baseline (251.570 us; speedup 1.0000x reference)
//
#include <hip/hip_runtime.h>
#include <stdint.h>

// MultiHeadAttentionProj: B=4, N=2048, D=512, H=8, HD=64
// cvtw (W->bf16 concat + q->bf16) -> gemm_qkv (pure gl_lds dbuf, 128x192,
// one full-drain barrier/step, grid 512 = 2/CU) -> attn (2-HEAD blocks,
// 512 thr = 8 waves = 2 heads x 4 waves x 32 q; bias loaded ONCE per tile,
// fused with mask into LDS (blds = bias*L2E + mask, pitch 68), consumed by
// both heads as MFMA C-init -> bias stream halves; per-wave math/layout
// byte-equivalent to R9) -> gemm_out (unchanged R10).
// R11 FIX: gemm_qkv B staging issues 6 gl_lds/wave (24 total = 1536 chunks),
// not 12 — the 12 overran Bt[0] into Bt[1] and read Wqkv OOB (absmax 0.73).

typedef __attribute__((ext_vector_type(8))) short short8;
typedef __attribute__((ext_vector_type(4))) short short4v;
typedef __attribute__((ext_vector_type(4))) float f32x4;

#define DEV static __device__ __forceinline__

constexpr int Bc = 4, Nc = 2048, Dc = 512, Hc = 8, HDc = 64;
constexpr int Mc = Bc * Nc;        // 8192 rows
constexpr int QKVNc = 3 * Dc;      // 1536
constexpr float L2E = 1.44269504f;

DEV short bf16cast(float f) {      // f32 -> bf16 bits (RNE via HW cvt)
  return (short)__builtin_bit_cast(unsigned short, (__bf16)f);
}
DEV unsigned cvt_pk_bf16(float a, float b) {  // a->low16, b->high16 (RNE)
  unsigned short lb = __builtin_bit_cast(unsigned short, (__bf16)a);
  unsigned short hb = __builtin_bit_cast(unsigned short, (__bf16)b);
  return (unsigned)lb | ((unsigned)hb << 16);
}
DEV unsigned pack_shorts(short a, short b) {
  return (unsigned)(unsigned short)a | ((unsigned)(unsigned short)b << 16);
}
DEV float fast_exp2(float x) {
#if __has_builtin(__builtin_amdgcn_exp2f)
  return __builtin_amdgcn_exp2f(x);
#else
  return exp2f(x);
#endif
}
// HW-verified (R3/R4): after op, a = [a.lo32, b.lo32], b = [a.hi32, b.hi32]
DEV void permswap32(unsigned& a, unsigned& b) {
  asm volatile("v_permlane32_swap_b32 %0, %1" : "+v"(a), "+v"(b));
}
// async global->LDS, 16B per lane; LDS dest = wave-uniform base + lane*16
DEV void gl_lds16(const short* g, short* l) {
  __builtin_amdgcn_global_load_lds(
      (const __attribute__((address_space(1))) void*)g,
      (__attribute__((address_space(3))) void*)l, 16, 0, 0);
}

// Blocks 0..1023: Wq,Wk,Wv -> Wqkv (bf16 concat), Wo -> Wob.
// Blocks 1024..5119: q (f32) -> qb (bf16).
__global__ void cvtw_kernel(const float* __restrict__ Wq, const float* __restrict__ Wk,
                            const float* __restrict__ Wv, const float* __restrict__ Wo,
                            const float* __restrict__ q,
                            short* __restrict__ Wqkv, short* __restrict__ Wob,
                            short* __restrict__ qb) {
  int bid = blockIdx.x;
  const float* src; short* dst; int j;
  if (bid < 1024) {                                  // weights: 4 x 256 blocks
    int which = bid >> 8;
    j = (bid & 255) * 256 + threadIdx.x;             // float4 index < 65536
    src = which == 0 ? Wq : which == 1 ? Wk : which == 2 ? Wv : Wo;
    dst = (which == 3) ? Wob : Wqkv + which * (Dc * Dc);
  } else {                                           // q: 4096 blocks
    j = (bid - 1024) * 256 + threadIdx.x;            // float4 index < 1048576
    src = q; dst = qb;
  }
  float4 v = ((const float4*)src)[j];
  short4v o = { bf16cast(v.x), bf16cast(v.y), bf16cast(v.z), bf16cast(v.w) };
  ((short4v*)dst)[j] = o;
}

// QKV[M][1536] = qb[M][512] @ Wqkv[1536][512]^T. 128x192 tiles, BK=64.
// Pure gl_lds, dbuf LDS, ONE full-drain barrier per K-step (loads issued
// after the barrier age through the whole compute phase).
__global__ __launch_bounds__(256, 2) void gemm_qkv(const short* __restrict__ qb,
                                                   const short* __restrict__ Wqkv,
                                                   short* __restrict__ QKV,
                                                   float cscale) {
  constexpr int K = 512;
  __shared__ __align__(16) short At[2][128 * 64];
  __shared__ __align__(16) short Bt[2][192 * 64];
  const int tid = threadIdx.x, lane = tid & 63, wv = tid >> 6;
  const int quad = lane >> 4, l16 = lane & 15;
  const int mbase = blockIdx.y * 128, nbase = blockIdx.x * 192;
  const int wr = (wv >> 1) * 64, wc = (wv & 1) * 96;
  f32x4 acc[4][6] = {};
#pragma unroll
  for (int i = 0; i < 4; i++) {                 // issue A, k0=0 -> At[0]
    int ibase = (wv * 4 + i) * 64;
    int row = (ibase + lane) >> 3, ch = lane & 7;
    gl_lds16(&qb[(size_t)(mbase + row) * K + ((ch ^ (row & 7)) << 3)],
             &At[0][ibase << 3]);
  }
#pragma unroll
  for (int i = 0; i < 6; i++) {                 // issue B, k0=0 -> Bt[0]  (24 total)
    int ibase = (wv * 6 + i) * 64;
    int row = (ibase + lane) >> 3, ch = lane & 7;
    gl_lds16(&Wqkv[(size_t)(nbase + row) * K + ((ch ^ (row & 7)) << 3)],
             &Bt[0][ibase << 3]);
  }
  for (int k0 = 0; k0 < K; k0 += 64) {
    const int cur = (k0 >> 6) & 1;
    __syncthreads();                            // buf[cur] ready (aged)
    if (k0 + 64 < K) {                          // issue next -> buf[cur^1]
#pragma unroll
      for (int i = 0; i < 4; i++) {
        int ibase = (wv * 4 + i) * 64;
        int row = (ibase + lane) >> 3, ch = lane & 7;
        gl_lds16(&qb[(size_t)(mbase + row) * K + k0 + 64 + ((ch ^ (row & 7)) << 3)],
                 &At[cur ^ 1][ibase << 3]);
      }
#pragma unroll
      for (int i = 0; i < 6; i++) {             // 24 total = 1536 chunks (fix)
        int ibase = (wv * 6 + i) * 64;
        int row = (ibase + lane) >> 3, ch = lane & 7;
        gl_lds16(&Wqkv[(size_t)(nbase + row) * K + k0 + 64 + ((ch ^ (row & 7)) << 3)],
                 &Bt[cur ^ 1][ibase << 3]);
      }
    }
#pragma unroll
    for (int s = 0; s < 2; s++) {
      short8 af[4], bf[6];
#pragma unroll
      for (int t = 0; t < 4; t++) {
        int r = wr + t * 16 + l16;
        af[t] = *(short8*)&At[cur][r * 64 + (((quad + 4 * s) ^ (r & 7)) << 3)];
      }
#pragma unroll
      for (int t = 0; t < 6; t++) {
        int r = wc + t * 16 + l16;
        bf[t] = *(short8*)&Bt[cur][r * 64 + (((quad + 4 * s) ^ (r & 7)) << 3)];
      }
#pragma unroll
      for (int mt = 0; mt < 4; mt++)
#pragma unroll
        for (int nt = 0; nt < 6; nt++)
          acc[mt][nt] = __builtin_amdgcn_mfma_f32_16x16x32_bf16(af[mt], bf[nt], acc[mt][nt], 0, 0, 0);
    }
  }
#pragma unroll
  for (int nt = 0; nt < 6; nt++) {
    const float sc = (nbase + wc + nt * 16 < 512) ? cscale : 1.0f;
#pragma unroll
    for (int mt = 0; mt < 4; mt++)
#pragma unroll
      for (int r = 0; r < 4; r++) {             // C/D: row=quad*4+r, col=l16
        int row = mbase + wr + mt * 16 + quad * 4 + r;
        int col = nbase + wc + nt * 16 + l16;
        QKV[(size_t)row * QKVNc + col] = bf16cast(acc[mt][nt][r] * sc);
      }
  }
}

// out[M][512] = aout[M][512] @ Wob[512][512]^T. Unchanged from R10 (verified).
__global__ __launch_bounds__(256, 2) void gemm_out(const short* __restrict__ aout,
                                                   const short* __restrict__ Wob,
                                                   float* __restrict__ out) {
  constexpr int K = 512;
  __shared__ __align__(16) short At[2][128 * 64];
  __shared__ __align__(16) short Bt[2][64 * 64];
  const int tid = threadIdx.x, lane = tid & 63, wv = tid >> 6;
  const int quad = lane >> 4, l16 = lane & 15;
  const int mbase = blockIdx.y * 128, nbase = blockIdx.x * 64;
  const int wr = wv * 32;
  f32x4 acc[2][4] = {};
#pragma unroll
  for (int i = 0; i < 4; i++) {
    int ibase = (wv * 4 + i) * 64;
    int row = (ibase + lane) >> 3, ch = lane & 7;
    gl_lds16(&aout[(size_t)(mbase + row) * K + ((ch ^ (row & 7)) << 3)],
             &At[0][ibase << 3]);
  }
#pragma unroll
  for (int i = 0; i < 2; i++) {
    int ibase = (wv * 2 + i) * 64;
    int row = (ibase + lane) >> 3, ch = lane & 7;
    gl_lds16(&Wob[(size_t)(nbase + row) * K + ((ch ^ (row & 7)) << 3)],
             &Bt[0][ibase << 3]);
  }
  for (int k0 = 0; k0 < K; k0 += 64) {
    const int cur = (k0 >> 6) & 1;
    __syncthreads();
    if (k0 + 64 < K) {
#pragma unroll
      for (int i = 0; i < 4; i++) {
        int ibase = (wv * 4 + i) * 64;
        int row = (ibase + lane) >> 3, ch = lane & 7;
        gl_lds16(&aout[(size_t)(mbase + row) * K + k0 + 64 + ((ch ^ (row & 7)) << 3)],
                 &At[cur ^ 1][ibase << 3]);
      }
#pragma unroll
      for (int i = 0; i < 2; i++) {
        int ibase = (wv * 2 + i) * 64;
        int row = (ibase + lane) >> 3, ch = lane & 7;
        gl_lds16(&Wob[(size_t)(nbase + row) * K + k0 + 64 + ((ch ^ (row & 7)) << 3)],
                 &Bt[cur ^ 1][ibase << 3]);
      }
    }
#pragma unroll
    for (int s = 0; s < 2; s++) {
      short8 af[2], bf[4];
#pragma unroll
      for (int t = 0; t < 2; t++) {
        int r = wr + t * 16 + l16;
        af[t] = *(short8*)&At[cur][r * 64 + (((quad + 4 * s) ^ (r & 7)) << 3)];
      }
#pragma unroll
      for (int t = 0; t < 4; t++) {
        int r = t * 16 + l16;
        bf[t] = *(short8*)&Bt[cur][r * 64 + (((quad + 4 * s) ^ (r & 7)) << 3)];
      }
#pragma unroll
      for (int mt = 0; mt < 2; mt++)
#pragma unroll
        for (int nt = 0; nt < 4; nt++)
          acc[mt][nt] = __builtin_amdgcn_mfma_f32_16x16x32_bf16(af[mt], bf[nt], acc[mt][nt], 0, 0, 0);
    }
  }
#pragma unroll
  for (int mt = 0; mt < 2; mt++)
#pragma unroll
    for (int nt = 0; nt < 4; nt++)
#pragma unroll
      for (int r = 0; r < 4; r++) {
        int row = mbase + wr + mt * 16 + quad * 4 + r;
        int col = nbase + nt * 16 + l16;
        out[(size_t)row * Dc + col] = acc[mt][nt][r];
      }
}

// Flash attention, 2-HEAD blocks. blockIdx.x = b*64 + qt*4 + hp (256 blocks,
// 1/CU). 512 thr = 8 waves: head = hp*2 + (wv>>2), each wave = 32 q-rows
// (R9-identical unit). bias loaded once per tile, fused with mask into
// blds[q][68-pitch] = bias*L2E + mask; both heads C-init from it.
__global__ __launch_bounds__(512, 2) void attn_kernel(const short* __restrict__ QKV,
                                                      const float* __restrict__ bias,
                                                      const void* __restrict__ mask,
                                                      short* __restrict__ Aout) {
  __shared__ __align__(16) short Kt[2][2][64 * 64];  // [head-half][buf][key][hd]
  __shared__ __align__(16) short Vt[2][2][64 * 64];  // [head-half][buf][hd][key_perm]
  __shared__ __align__(16) float blds[2][128 * 68];  // fused bias*L2E+mask, pitch 68
  __shared__ __align__(16) float mlds[Nc];
  __shared__ int mflag;
  const int tid = threadIdx.x, lane = tid & 63, wv = tid >> 6;   // wv 0..7
  const int quad = lane >> 4, l16 = lane & 15;
  const int hp = blockIdx.x & 3, qt = (blockIdx.x >> 2) & 15, b = (int)(blockIdx.x >> 6);
  const int hw = wv >> 2;                            // head half 0/1
  const int h = hp * 2 + hw;
  const int wq = wv & 3;
  const int qrow0 = qt * 128;
  const int q0 = qrow0 + wq * 32 + l16;              // n=0 q-row; n=1 is q0+16
  const short* Kbase = QKV + Dc + h * HDc;
  const short* Vbase = QKV + 2 * Dc + h * HDc;

  // ---- issue K gl_lds tile 0 (this wave's head) ----
#pragma unroll
  for (int g = 0; g < 2; g++) {
    int seg = (wv & 3) * 2 + g, c = seg * 64 + lane;
    int row = c >> 3, ch = c & 7;
    gl_lds16(&Kbase[(size_t)(b * Nc + row) * QKVNc + ((ch ^ (row & 7)) << 3)],
             &Kt[hw][0][seg * 512]);
  }

  short8 qf[2][2];  // [n][s]: Q (pre-scaled 0.125*log2e)
  {
    const short* qp0 = QKV + (size_t)(b * Nc + q0) * QKVNc + h * HDc + quad * 8;
    qf[0][0] = *(const short8*)qp0;
    qf[0][1] = *(const short8*)(qp0 + 32);
    const short* qp1 = qp0 + (size_t)16 * QKVNc;
    qf[1][0] = *(const short8*)qp1;
    qf[1][1] = *(const short8*)(qp1 + 32);
  }

  // V staging: lower/upper 256 threads stage their own head's V
  const int lt = tid & 255;
  const int vp = lt & 31, vq = lt >> 5;              // key-pair 0..31, hd-oct 0..7
  const int vperm = (vp & 25) | ((vp & 4) >> 1) | ((vp & 2) << 1);  // key bits 3<->2
  const int vwbase = (((vperm >> 2)) << 3) + 2 * (vperm & 3);

  short8 v0pre, v1pre;
  v0pre = *(const short8*)&Vbase[(size_t)(b * Nc + 2 * vp) * QKVNc + vq * 8];
  v1pre = *(const short8*)&Vbase[(size_t)(b * Nc + 2 * vp + 1) * QKVNc + vq * 8];

  // bias staging: thread -> (q-row = tid>>2, 16-key chunk = (tid&3)*16)
  const int bq = tid >> 2, bc4 = (tid & 3) * 16;
  const float* biasP = bias + ((size_t)b * Nc + qrow0 + bq) * Nc;
  float4 bpre[4];
#pragma unroll
  for (int j = 0; j < 4; j++) bpre[j] = *(const float4*)&biasP[bc4 + 4 * j];

  // ---- inline mask convert (512 thr) ----
  if (tid == 0) mflag = 0;
  __syncthreads();
  {
    const uchar4* mw = (const uchar4*)((const char*)mask + (size_t)b * 2048);
    int acc = 0;
    for (int i = tid; i < 512; i += 512) {
      uchar4 v = mw[i];
      acc |= (int)v.y | (int)v.z | (int)v.w;
    }
    if (acc) atomicOr(&mflag, 1);
  }
  __syncthreads();
  {
    int isbyte = mflag;
    const unsigned char* mb = (const unsigned char*)mask + (size_t)b * 2048;
    const int* mi = (const int*)mask + (size_t)b * 2048;
    for (int i = tid; i < Nc; i += 512) {
      int v = isbyte ? (int)mb[i] : mi[i];
      mlds[i] = v ? -1e30f : 0.0f;
    }
  }

  const short ONEB = (short)0x3F80;                  // bf16 1.0
  const short8 ones = { ONEB, ONEB, ONEB, ONEB, ONEB, ONEB, ONEB, ONEB };

  f32x4 oacc[2][4] = {};                             // [m][t]
  f32x4 sumacc[2] = {};

  for (int kt = 0; kt < 32; kt++) {
    const int cur = kt & 1;
    const int kb = kt * 64;
    const int kbn = ((kt + 1) & 31) * 64;            // wraps, in-bounds

    // W: V regs -> Vt[hw][cur]; blds[cur] = bias*L2E + mask (fused, once)
#pragma unroll
    for (int jj = 0; jj < 8; jj++) {
      int hd = vq * 8 + jj;
      *(unsigned*)&Vt[hw][cur][hd * 64 + (vwbase ^ ((hd & 7) << 3))] =
          pack_shorts(v0pre[jj], v1pre[jj]);
    }
#pragma unroll
    for (int j = 0; j < 4; j++) {
      float4 m = *(const float4*)&mlds[kb + bc4 + 4 * j];
      float4 o = { __builtin_fmaf(bpre[j].x, L2E, m.x), __builtin_fmaf(bpre[j].y, L2E, m.y),
                   __builtin_fmaf(bpre[j].z, L2E, m.z), __builtin_fmaf(bpre[j].w, L2E, m.w) };
      *(float4*)&blds[cur][bq * 68 + bc4 + 4 * j] = o;
    }
    __syncthreads();                                 // drains gl_lds K[cur] too

    // L: issue next tile: K gl_lds -> Kt[hw][cur^1]; V + bias -> regs
#pragma unroll
    for (int g = 0; g < 2; g++) {
      int seg = (wv & 3) * 2 + g, c = seg * 64 + lane;
      int row = c >> 3, ch = c & 7;
      gl_lds16(&Kbase[(size_t)(b * Nc + kbn + row) * QKVNc + ((ch ^ (row & 7)) << 3)],
               &Kt[hw][cur ^ 1][seg * 512]);
    }
    v0pre = *(const short8*)&Vbase[(size_t)(b * Nc + kbn + 2 * vp) * QKVNc + vq * 8];
    v1pre = *(const short8*)&Vbase[(size_t)(b * Nc + kbn + 2 * vp + 1) * QKVNc + vq * 8];
#pragma unroll
    for (int j = 0; j < 4; j++) bpre[j] = *(const float4*)&biasP[kbn + bc4 + 4 * j];

    // C-init = blds (fused bias+mask); per-lane q-row, per-reg key
    f32x4 sacc[2][4];
#pragma unroll
    for (int n = 0; n < 2; n++)
#pragma unroll
      for (int t = 0; t < 4; t++)
        sacc[n][t] = *(f32x4*)&blds[cur][(wq * 32 + n * 16 + l16) * 68 + t * 16 + quad * 4];

    // QK^T: S^T[key=16t+4quad+r][q=n*16+l16]
    __builtin_amdgcn_s_setprio(1);
#pragma unroll
    for (int s = 0; s < 2; s++)
#pragma unroll
      for (int t = 0; t < 4; t++) {
        short8 kf = *(short8*)&Kt[hw][cur][(t * 16 + l16) * 64 + (((quad + 4 * s) ^ (l16 & 7)) << 3)];
        sacc[0][t] = __builtin_amdgcn_mfma_f32_16x16x32_bf16(kf, qf[0][s], sacc[0][t], 0, 0, 0);
        sacc[1][t] = __builtin_amdgcn_mfma_f32_16x16x32_bf16(kf, qf[1][s], sacc[1][t], 0, 0, 0);
      }
    __builtin_amdgcn_s_setprio(0);

    // softmax: p = exp2(sacc) (bias/mask already folded); pack; permute
    short8 pf[2][2];
#pragma unroll
    for (int n = 0; n < 2; n++) {
      unsigned pw[4][2];
#pragma unroll
      for (int t = 0; t < 4; t++) {
        float p0 = fast_exp2(sacc[n][t][0]);
        float p1 = fast_exp2(sacc[n][t][1]);
        float p2 = fast_exp2(sacc[n][t][2]);
        float p3 = fast_exp2(sacc[n][t][3]);
        pw[t][0] = cvt_pk_bf16(p0, p1);
        pw[t][1] = cvt_pk_bf16(p2, p3);
      }
      permswap32(pw[0][0], pw[1][0]); permswap32(pw[0][1], pw[1][1]);
      permswap32(pw[2][0], pw[3][0]); permswap32(pw[2][1], pw[3][1]);
      union { unsigned u[4]; short8 s; }
          a0{{pw[0][0], pw[0][1], pw[1][0], pw[1][1]}},
          a1{{pw[2][0], pw[2][1], pw[3][0], pw[3][1]}};
      pf[n][0] = a0.s; pf[n][1] = a1.s;
    }

    // PV: O += P·V (permuted contraction); rowsum += P·1
    __builtin_amdgcn_s_setprio(1);
#pragma unroll
    for (int s = 0; s < 2; s++) {
      sumacc[0] = __builtin_amdgcn_mfma_f32_16x16x32_bf16(pf[0][s], ones, sumacc[0], 0, 0, 0);
      sumacc[1] = __builtin_amdgcn_mfma_f32_16x16x32_bf16(pf[1][s], ones, sumacc[1], 0, 0, 0);
#pragma unroll
      for (int t = 0; t < 4; t++) {
        short8 vf = *(short8*)&Vt[hw][cur][(t * 16 + l16) * 64 + (((quad + 4 * s) ^ (l16 & 7)) << 3)];
        oacc[0][t] = __builtin_amdgcn_mfma_f32_16x16x32_bf16(pf[0][s], vf, oacc[0][t], 0, 0, 0);
        oacc[1][t] = __builtin_amdgcn_mfma_f32_16x16x32_bf16(pf[1][s], vf, oacc[1][t], 0, 0, 0);
      }
    }
    __builtin_amdgcn_s_setprio(0);
  }

#pragma unroll
  for (int m = 0; m < 2; m++)
#pragma unroll
    for (int r = 0; r < 4; r++) {                    // O row q=m*16+quad*4+r
      float inv = 1.0f / sumacc[m][r];
      int row = b * Nc + qrow0 + wq * 32 + m * 16 + quad * 4 + r;
#pragma unroll
      for (int t = 0; t < 4; t++)
        Aout[(size_t)row * Dc + h * HDc + t * 16 + l16] = bf16cast(oacc[m][t][r] * inv);
    }
}

extern "C" void kernel_launch(void* const* d_in, const int* in_sizes, int n_in,
                              void* d_out, int out_size, void* d_ws, size_t ws_size,
                              hipStream_t stream) {
  const float* q    = (const float*)d_in[0];
  const void*  mask = d_in[1];
  const float* bias = (const float*)d_in[2];
  const float* Wq   = (const float*)d_in[3];
  const float* Wk   = (const float*)d_in[4];
  const float* Wv   = (const float*)d_in[5];
  const float* Wo   = (const float*)d_in[6];
  float* out = (float*)d_out;

  char* ws = (char*)d_ws;
  short* Wqkv = (short*)ws;  ws += (size_t)QKVNc * Dc * 2;
  short* Wob  = (short*)ws;  ws += (size_t)Dc * Dc * 2;
  short* qb   = (short*)ws;  ws += (size_t)Mc * Dc * 2;
  short* QKV  = (short*)ws;  ws += (size_t)Mc * QKVNc * 2;
  short* aout = (short*)ws;  ws += (size_t)Mc * Dc * 2;

  cvtw_kernel<<<dim3(5120), dim3(256), 0, stream>>>(Wq, Wk, Wv, Wo, q, Wqkv, Wob, qb);

  // Q cols pre-scaled by 0.125*log2e so attn can use exp2 directly.
  gemm_qkv<<<dim3(QKVNc / 192, Mc / 128), dim3(256), 0, stream>>>(
      qb, Wqkv, QKV, 0.125f * L2E);
  attn_kernel<<<dim3(Bc * 16 * 4), dim3(512), 0, stream>>>(QKV, bias, mask, aout);
  gemm_out<<<dim3(Dc / 64, Mc / 128), dim3(256), 0, stream>>>(aout, Wob, out);
}